// Round 5
// baseline (603.764 us; speedup 1.0000x reference)
//
#include <hip/hip_runtime.h>

typedef unsigned short ush;
typedef __attribute__((ext_vector_type(8))) __bf16 bf16x8;
typedef __attribute__((ext_vector_type(4))) float f32x4;

#define NE 33554432L  // 4*128*128*512 elements per Q/K/V matrix

// ---------- bf16 <-> fp32 helpers (RNE) ----------
__device__ __forceinline__ float b2f(ush u) {
  return __uint_as_float(((unsigned int)u) << 16);
}
__device__ __forceinline__ ush f2b(float f) {
  unsigned int x = __float_as_uint(f);
  x += 0x7fffu + ((x >> 16) & 1u);
  return (ush)(x >> 16);
}
__device__ __forceinline__ bf16x8 bc8(int4 v) { return __builtin_bit_cast(bf16x8, v); }

// async 16B global->LDS (wave-uniform LDS base + lane*16)
__device__ __forceinline__ void gload16(const ush* g, ush* l) {
  __builtin_amdgcn_global_load_lds(
      (const __attribute__((address_space(1))) void*)g,
      (__attribute__((address_space(3))) void*)l, 16, 0, 0);
}

// ---------- kernel: input dtype sniffer ----------
__global__ __launch_bounds__(256)
void detect_dtype(const ush* __restrict__ x, int* __restrict__ flag) {
  __shared__ int red[256];
  const int t = threadIdx.x;
  int cnt = 0;
  for (int i = t; i < 16384; i += 256) {
    const int e = (x[i] >> 7) & 0xFF;
    cnt += (e == 0 || (e >= 100 && e <= 142)) ? 1 : 0;
  }
  red[t] = cnt;
  __syncthreads();
  for (int s = 128; s > 0; s >>= 1) {
    if (t < s) red[t] += red[t + s];
    __syncthreads();
  }
  if (t == 0) flag[0] = (red[0] >= 13107) ? 1 : 0;  // 80% of 16384
}

// ---------- kernel: pack x -> bf16 ----------
__global__ __launch_bounds__(256)
void pack_x(const void* __restrict__ xin, ush* __restrict__ xb,
            const int* __restrict__ flag) {
  const long i0 = ((long)blockIdx.x * 256 + threadIdx.x) * 8;
  if (*flag) {
    *(int4*)&xb[i0] = *(const int4*)&((const ush*)xin)[i0];
  } else {
    const float* xf = (const float*)xin;
    const float4 a = *(const float4*)&xf[i0];
    const float4 b = *(const float4*)&xf[i0 + 4];
    union { ush u[8]; int4 v; } r;
    r.u[0] = f2b(a.x); r.u[1] = f2b(a.y); r.u[2] = f2b(a.z); r.u[3] = f2b(a.w);
    r.u[4] = f2b(b.x); r.u[5] = f2b(b.y); r.u[6] = f2b(b.z); r.u[7] = f2b(b.w);
    *(int4*)&xb[i0] = r.v;
  }
}

// ---------- kernel: pack+transpose weights -> bf16 wT[n][k] = w[k][n] ----------
__global__ __launch_bounds__(256)
void pack_w(const void* __restrict__ w0, const void* __restrict__ w1,
            const void* __restrict__ w2, ush* __restrict__ wTb,
            const int* __restrict__ flag) {
  __shared__ ush tile[32][33];
  const void* w = (blockIdx.z == 0) ? w0 : ((blockIdx.z == 1) ? w1 : w2);
  ush* wT = wTb + (long)blockIdx.z * 262144;
  const int bx = blockIdx.x * 32, by = blockIdx.y * 32;
  const int tx = threadIdx.x & 31, ty = threadIdx.x >> 5;
  const int f = *flag;
#pragma unroll
  for (int j = 0; j < 32; j += 8) {
    const int k = by + ty + j, n = bx + tx;
    tile[ty + j][tx] = f ? ((const ush*)w)[k * 512 + n]
                         : f2b(((const float*)w)[k * 512 + n]);
  }
  __syncthreads();
#pragma unroll
  for (int j = 0; j < 32; j += 8)
    wT[(bx + ty + j) * 512 + by + tx] = tile[tx][ty + j];
}

// ---------- kernel: pack biases -> fp32 ----------
__global__ void pack_bias(const void* __restrict__ b0, const void* __restrict__ b1,
                          const void* __restrict__ b2, float* __restrict__ biasf,
                          const int* __restrict__ flag) {
  const void* b = (blockIdx.x == 0) ? b0 : ((blockIdx.x == 1) ? b1 : b2);
  const int n = threadIdx.x;
  const float v = (*flag) ? b2f(((const ush*)b)[n]) : ((const float*)b)[n];
  biasf[blockIdx.x * 512 + n] = v;
}

// ---------- kernel: QKV projection GEMM (256^2 tile, counted-vmcnt pipeline) ----------
// BM=BN=256, BK=32, 8 waves (2M x 4N), wave tile 128x64. Tri-buffered LDS
// (3 x 32KB), staging TWO K-tiles ahead via global_load_lds; raw s_barrier +
// s_waitcnt vmcnt(4) per K-tile (never 0 mid-loop -> loads stay in flight
// across barriers, T3+T4). LDS k-slot XOR swizzle (slot ^= (row>>1)&3, both
// sides) keeps ds_read_b128 fragment reads 2-way max (free).
__global__ __launch_bounds__(512, 2)
void proj_gemm(const ush* __restrict__ xb, const ush* __restrict__ wTb,
               const float* __restrict__ biasf, ush* __restrict__ qkv) {
  __shared__ ush plds[49152];  // 3 bufs x (A[256][32] + B[256][32]) = 96 KB

  // bijective XCD swizzle: 1536 blocks, 192/XCD chunk, z-major within chunk
  const int lin = blockIdx.x;
  const int wg = (lin & 7) * 192 + (lin >> 3);
  const int mb = wg & 255, nb = (wg >> 8) & 1, z = wg >> 9;

  const ush* wt = wTb + (long)z * 262144;
  const float* bias = biasf + z * 512;
  ush* out = qkv + (long)z * NE;

  const int t = threadIdx.x;
  const int lane = t & 63, wvid = t >> 6;   // 8 waves
  const int wm = wvid >> 2, wn = wvid & 3;  // 2M x 4N
  const int col = lane & 15, quad = lane >> 4;

  const long m0 = (long)mb * 256;
  const int n0 = nb * 256;

  // staging: one gload16/wave covers 16 rows x 32k (1KB). lane l -> row l>>2,
  // slot l&3; source k-slot pre-swizzled by (row>>1)&3 = (l>>3)&3.
  const int srow = lane >> 2;
  const int sslot = ((lane & 3) ^ ((lane >> 3) & 3)) * 8;
  const ush* gA0 = xb + (m0 + wvid * 16 + srow) * 512 + sslot;
  const ush* gA1 = xb + (m0 + 128 + wvid * 16 + srow) * 512 + sslot;
  const ush* gB0 = wt + (long)(n0 + wvid * 16 + srow) * 512 + sslot;
  const ush* gB1 = wt + (long)(n0 + 128 + wvid * 16 + srow) * 512 + sslot;
  const int dA0 = wvid * 512;          // ush offset of wave's 16-row group
  const int dA1 = 4096 + wvid * 512;

  // fragment ds_read k-offset: slot = quad ^ ((row>>1)&3), row&1 flips bank half
  const int kofs = ((quad ^ ((col >> 1) & 3)) * 8);

#define PSTAGE(buf, kt) do {                              \
    ush* ab_ = plds + (buf) * 16384;                      \
    const int ko_ = (kt) * 32;                            \
    gload16(gA0 + ko_, ab_ + dA0);                        \
    gload16(gA1 + ko_, ab_ + dA1);                        \
    gload16(gB0 + ko_, ab_ + 8192 + dA0);                 \
    gload16(gB1 + ko_, ab_ + 8192 + dA1);                 \
  } while (0)

  const f32x4 z4 = {0.f, 0.f, 0.f, 0.f};
  f32x4 acc[8][4];
#pragma unroll
  for (int mt = 0; mt < 8; mt++)
#pragma unroll
    for (int nt = 0; nt < 4; nt++) acc[mt][nt] = z4;

  // prologue: stage tiles 0,1
  PSTAGE(0, 0);
  PSTAGE(1, 1);
  asm volatile("s_waitcnt vmcnt(4)" ::: "memory");  // tile 0 landed
  asm volatile("s_barrier" ::: "memory");

  int cur = 0;
  for (int kt = 0; kt < 16; ++kt) {
    if (kt < 14) {
      int n2 = cur + 2; if (n2 >= 3) n2 -= 3;
      PSTAGE(n2, kt + 2);                 // issue 2-ahead BEFORE compute
    }
    const ush* Ab = plds + cur * 16384;
    const ush* Bb = Ab + 8192;
    bf16x8 a[8], bb[4];
#pragma unroll
    for (int mt = 0; mt < 8; mt++)
      a[mt] = bc8(*(const int4*)&Ab[(wm * 128 + mt * 16 + col) * 32 + kofs]);
#pragma unroll
    for (int nt = 0; nt < 4; nt++)
      bb[nt] = bc8(*(const int4*)&Bb[(wn * 64 + nt * 16 + col) * 32 + kofs]);
    __builtin_amdgcn_s_setprio(1);
#pragma unroll
    for (int mt = 0; mt < 8; mt++)
#pragma unroll
      for (int nt = 0; nt < 4; nt++)
        acc[mt][nt] = __builtin_amdgcn_mfma_f32_16x16x32_bf16(a[mt], bb[nt], acc[mt][nt], 0, 0, 0);
    __builtin_amdgcn_s_setprio(0);
    if (kt < 15) {
      if (kt < 14) asm volatile("s_waitcnt vmcnt(4)" ::: "memory");  // next tile landed, 2-ahead still flying
      else         asm volatile("s_waitcnt vmcnt(0)" ::: "memory");  // last tile
      asm volatile("s_barrier" ::: "memory");
    }
    cur = (cur < 2) ? cur + 1 : 0;
  }
#undef PSTAGE

#pragma unroll
  for (int nt = 0; nt < 4; nt++) {
    const int n = n0 + wn * 64 + nt * 16 + col;
    const float bbv = bias[n];
#pragma unroll
    for (int mt = 0; mt < 8; mt++) {
      const long row0 = m0 + wm * 128 + mt * 16 + quad * 4;
#pragma unroll
      for (int r = 0; r < 4; r++)
        out[(row0 + r) * 512 + n] = f2b(acc[mt][nt][r] + bbv);
    }
  }
}

// ---------- MFMA axial attention: multi-head blocks + reg-prefetch ----------
// PASS 1 (column): block (w=pp, b); loops ALL 8 heads. rows = H. Writes xv
//                  in-place over V (bf16) via LDS-staged full-line int4 stores.
// PASS 2 (row):    block (h=pp, b_local, headgrp); loops 4 heads. rows = W.
//                  Writes xu [bl][n][h][w][d]: bf16 when flag=1 (values
//                  identical: f2b just moves here from out_interleave),
//                  fp32 when flag=0.
#define QS_STRIDE 72    // bf16, 144 B rows (16B aligned), uniform bank groups
#define VT_STRIDE 136   // Vt[d][g], 272 B rows
#define P_STRIDE  136
#define OS_STRIDE 72    // pass-1 output staging rows (16B aligned)

__device__ __forceinline__ int vt_idx(int d, int g) {
  return d * VT_STRIDE + ((((g >> 3) ^ ((d >> 3) & 7)) << 3) | (g & 7));
}

template<int PASS>
__global__ __launch_bounds__(512, 4)
void axial_attn_mfma(const ush* __restrict__ Qb, const ush* __restrict__ Kb,
                     ush* __restrict__ Vb, void* __restrict__ xuf,
                     const int* __restrict__ flagp, const int bofs) {
  __shared__ ush smem[(PASS == 1) ? 36352 : 27136];
  ush* Qs = smem;                      // [128][72]
  ush* Ks = smem + 9216;               // [128][72]
  ush* Vt = smem + 18432;              // [64][136] swizzled
  ush* P  = smem;                      // [128][136] overlays Qs+Ks after bar1
  ush* Os = smem + 27136;              // [128][72] (PASS 1 only)

  const int flg = (PASS == 2) ? *flagp : 0;
  const int pp = blockIdx.x;
  const int NH = (PASS == 1) ? 8 : 4;
  const int b = blockIdx.y + ((PASS == 1) ? 0 : bofs);
  const int nstart = (PASS == 1) ? 0 : (blockIdx.z * 4);

  long base0; int stride;
  if (PASS == 1) { base0 = ((long)b * 16384 + pp) * 512; stride = 65536; }
  else           { base0 = ((long)(b * 128 + pp) * 128) * 512; stride = 512; }

  const int t = threadIdx.x;
  const int srow0 = t >> 3, c8 = t & 7;          // staging: rows srow0, srow0+64
  const long o0 = base0 + (long)srow0 * stride + c8 * 8;
  const long o1 = base0 + (long)(srow0 + 64) * stride + c8 * 8;

  const int lane = t & 63, wv = t >> 6;   // wv in [0,8)
  const int col = lane & 15, quad = lane >> 4;
  const int m0 = wv * 16;                 // wave owns rows m0..m0+15
  const f32x4 z4 = {0.f, 0.f, 0.f, 0.f};
  const float CLIP = 1.0f - 1e-7f;

  int4 qr0, qr1, kr0, kr1, vr0, vr1;
#define LOADH(nn_) do { const long nn = (long)(nn_) * 64;          \
    qr0 = *(const int4*)(Qb + o0 + nn); qr1 = *(const int4*)(Qb + o1 + nn); \
    kr0 = *(const int4*)(Kb + o0 + nn); kr1 = *(const int4*)(Kb + o1 + nn); \
    vr0 = *(const int4*)(Vb + o0 + nn); vr1 = *(const int4*)(Vb + o1 + nn); \
  } while (0)

  LOADH(nstart);

  for (int hn = 0; hn < NH; ++hn) {
    const int n = nstart + hn;
    // ---- stage current head from regs (prev PV reads done at prev bar3) ----
    *(int4*)&Qs[srow0 * QS_STRIDE + c8 * 8] = qr0;
    *(int4*)&Qs[(srow0 + 64) * QS_STRIDE + c8 * 8] = qr1;
    *(int4*)&Ks[srow0 * QS_STRIDE + c8 * 8] = kr0;
    *(int4*)&Ks[(srow0 + 64) * QS_STRIDE + c8 * 8] = kr1;
    {
      union { int4 i4; ush u[8]; } vu;
      vu.i4 = vr0;
#pragma unroll
      for (int dd = 0; dd < 8; dd++) Vt[vt_idx(c8 * 8 + dd, srow0)] = vu.u[dd];
      vu.i4 = vr1;
#pragma unroll
      for (int dd = 0; dd < 8; dd++) Vt[vt_idx(c8 * 8 + dd, srow0 + 64)] = vu.u[dd];
    }
    __syncthreads();                      // barA: stage visible
    if (hn + 1 < NH) LOADH(n + 1);        // prefetch next head under compute

    // ---- S = Q K^T : 1 m-tile x 8 n-tiles x 2 k-steps ----
    f32x4 sacc[8];
#pragma unroll
    for (int j = 0; j < 8; j++) sacc[j] = z4;
    __builtin_amdgcn_s_setprio(1);
#pragma unroll
    for (int k0 = 0; k0 < 64; k0 += 32) {
      bf16x8 a, kb[8];
      a = bc8(*(const int4*)&Qs[(m0 + col) * QS_STRIDE + k0 + quad * 8]);
#pragma unroll
      for (int j = 0; j < 8; j++)
        kb[j] = bc8(*(const int4*)&Ks[(j * 16 + col) * QS_STRIDE + k0 + quad * 8]);
#pragma unroll
      for (int j = 0; j < 8; j++)
        sacc[j] = __builtin_amdgcn_mfma_f32_16x16x32_bf16(a, kb[j], sacc[j], 0, 0, 0);
    }
    __builtin_amdgcn_s_setprio(0);

    // ---- softmax (faithful: clip +-(1-eps), /8, exp, sum, clip [eps,1-eps]) ----
    float e[8][4], inv[4];
#pragma unroll
    for (int r = 0; r < 4; r++) {
      float part = 0.f;
#pragma unroll
      for (int j = 0; j < 8; j++) {
        float s = sacc[j][r];
        s = fminf(fmaxf(s, -CLIP), CLIP) * 0.125f;
        const float ee = __expf(s);
        e[j][r] = ee;
        part += ee;
      }
      part += __shfl_xor(part, 1);
      part += __shfl_xor(part, 2);
      part += __shfl_xor(part, 4);
      part += __shfl_xor(part, 8);
      inv[r] = 1.0f / part;
    }
    __syncthreads();  // bar1: Qs/Ks reads complete -> safe to overlay P

#pragma unroll
    for (int r = 0; r < 4; r++) {
      const int row = m0 + quad * 4 + r;
#pragma unroll
      for (int j = 0; j < 8; j++) {
        const float pv = fminf(fmaxf(e[j][r] * inv[r], 1e-7f), CLIP);
        P[row * P_STRIDE + j * 16 + col] = f2b(pv);
      }
    }
    __syncthreads();  // bar2: P complete

    // ---- xv = P V : 1 m-tile x 4 n-tiles x 4 k-steps ----
    f32x4 oacc[4];
#pragma unroll
    for (int j = 0; j < 4; j++) oacc[j] = z4;
    __builtin_amdgcn_s_setprio(1);
#pragma unroll
    for (int k0 = 0; k0 < 128; k0 += 32) {
      bf16x8 a, vb[4];
      a = bc8(*(const int4*)&P[(m0 + col) * P_STRIDE + k0 + quad * 8]);
#pragma unroll
      for (int j = 0; j < 4; j++)
        vb[j] = bc8(*(const int4*)&Vt[vt_idx(j * 16 + col, k0 + quad * 8)]);
#pragma unroll
      for (int j = 0; j < 4; j++)
        oacc[j] = __builtin_amdgcn_mfma_f32_16x16x32_bf16(a, vb[j], oacc[j], 0, 0, 0);
    }
    __builtin_amdgcn_s_setprio(0);
    __syncthreads();  // bar3: P/Vt reads done -> regions free for next head

    // ---- epilogue for head n ----
    if (PASS == 1) {
#pragma unroll
      for (int r = 0; r < 4; r++) {
        const int row = m0 + quad * 4 + r;
#pragma unroll
        for (int j = 0; j < 4; j++)
          Os[row * OS_STRIDE + j * 16 + col] = f2b(oacc[j][r]);
      }
      __syncthreads();  // bar4: Os complete
      *(int4*)&Vb[o0 + (long)n * 64] = *(const int4*)&Os[srow0 * OS_STRIDE + c8 * 8];
      *(int4*)&Vb[o1 + (long)n * 64] = *(const int4*)&Os[(srow0 + 64) * OS_STRIDE + c8 * 8];
    } else {
      const long xbase = (((long)(blockIdx.y * 8 + n) * 128 + pp) * 128) * 64;
      if (flg) {
        ush* xw = (ush*)xuf;
#pragma unroll
        for (int r = 0; r < 4; r++) {
          const int row = m0 + quad * 4 + r;
#pragma unroll
          for (int j = 0; j < 4; j++)
            xw[xbase + (long)row * 64 + j * 16 + col] = f2b(oacc[j][r]);
        }
      } else {
        float* xf = (float*)xuf;
#pragma unroll
        for (int r = 0; r < 4; r++) {
          const int row = m0 + quad * 4 + r;
#pragma unroll
          for (int j = 0; j < 4; j++)
            xf[xbase + (long)row * 64 + j * 16 + col] = oacc[j][r];
        }
      }
    }
  }
#undef LOADH
}

// ---------- kernel: xu[bl][n][h][w][d] -> out[b][h][w][d*8+n], coalesced ----------
// LDS [8][16][64] with per-n d-rotation (d+8n)&63 (bank-spread both sides).
// bf16 path when flag=1 (xu is ush), fp32 path when flag=0.
__global__ __launch_bounds__(256)
void out_interleave(const void* __restrict__ xu, void* __restrict__ outp,
                    const int* __restrict__ flagp, const int bofs) {
  __shared__ float ldsf[8192];  // 32 KB (fp32) / 16 KB used (bf16)
  const int bz = blockIdx.z, h = blockIdx.y, w0 = blockIdx.x * 16;
  const int t = threadIdx.x;
  const int flg = *flagp;
  const long obase = (((long)(bz + bofs) * 128 + h) * 128 + w0) * 512;
  const int tc = t & 127, c0 = tc * 4;
  const int d = c0 >> 3, n0 = c0 & 7;  // n0 in {0,4}; c0..c0+3 share d

  if (flg) {
    ush* lds = (ush*)ldsf;
#pragma unroll
    for (int n = 0; n < 8; n++) {
      const ush* src = (const ush*)xu + ((((long)(bz * 8 + n)) * 128 + h) * 128 + w0) * 64;
      const int e = t * 4, w = e >> 6, dd = e & 63;
      const int2 v = *(const int2*)&src[e];
      const int dr = (dd + n * 8) & 63;  // no wrap inside 4 (dd%4==0, rot%8==0)
      *(int2*)&lds[(n * 16 + w) * 64 + dr] = v;
    }
    __syncthreads();
#pragma unroll
    for (int ro = 0; ro < 8; ro++) {
      const int w = (t >> 7) * 8 + ro;
      union { ush u[4]; int2 v; } o;
#pragma unroll
      for (int k = 0; k < 4; k++) {
        const int n = n0 + k;
        o.u[k] = lds[(n * 16 + w) * 64 + ((d + n * 8) & 63)];
      }
      *(int2*)&((ush*)outp)[obase + (long)w * 512 + c0] = o.v;
    }
  } else {
#pragma unroll
    for (int n = 0; n < 8; n++) {
      const float* src = (const float*)xu + ((((long)(bz * 8 + n)) * 128 + h) * 128 + w0) * 64;
      const int e = t * 4, w = e >> 6, dd = e & 63;
      const float4 v = *(const float4*)&src[e];
      const int dr = (dd + n * 8) & 63;
      *(float4*)&ldsf[(n * 16 + w) * 64 + dr] = v;
    }
    __syncthreads();
#pragma unroll
    for (int ro = 0; ro < 8; ro++) {
      const int w = (t >> 7) * 8 + ro;
      float4 o;
      o.x = ldsf[((n0 + 0) * 16 + w) * 64 + ((d + (n0 + 0) * 8) & 63)];
      o.y = ldsf[((n0 + 1) * 16 + w) * 64 + ((d + (n0 + 1) * 8) & 63)];
      o.z = ldsf[((n0 + 2) * 16 + w) * 64 + ((d + (n0 + 2) * 8) & 63)];
      o.w = ldsf[((n0 + 3) * 16 + w) * 64 + ((d + (n0 + 3) * 8) & 63)];
      *(float4*)&((float*)outp)[obase + (long)w * 512 + c0] = o;
    }
  }
}

// ---------- host ----------
extern "C" void kernel_launch(void* const* d_in, const int* in_sizes, int n_in,
                              void* d_out, int out_size, void* d_ws, size_t ws_size,
                              hipStream_t stream) {
  const void* x  = d_in[0];
  const void* wq = d_in[1];
  const void* bq = d_in[2];
  const void* wk = d_in[3];
  const void* bk = d_in[4];
  const void* wv = d_in[5];
  const void* bv = d_in[6];

  char* ws = (char*)d_ws;
  int*   flag  = (int*)ws;                       // @0
  float* biasf = (float*)(ws + 256);             // 3*512 fp32
  ush*   wTb   = (ush*)(ws + 8192);              // 1.5 MB
  ush*   xb    = (ush*)(ws + 8192 + 1572864);    // 64 MB (xu reuses after proj)
  void*  xuf   = (void*)(ws + 8192 + 1572864);   // xu: bf16 (33MB) or fp32 (67MB)
  ush*   qkv   = (ush*)(ws + 8192 + 1572864 + 67108864);  // 3*64 MB bf16

  dim3 blk(256);
  detect_dtype<<<1, blk, 0, stream>>>((const ush*)x, flag);
  pack_bias<<<3, 512, 0, stream>>>(bq, bk, bv, biasf, flag);
  pack_w<<<dim3(16, 16, 3), blk, 0, stream>>>(wq, wk, wv, wTb, flag);
  pack_x<<<16384, blk, 0, stream>>>(x, xb, flag);

  ush* Q = qkv;
  ush* K = Q + NE;
  ush* V = K + NE;
  proj_gemm<<<1536, dim3(512), 0, stream>>>(xb, wTb, biasf, Q);
  // pass 1: 512 blocks (w, b), 8-head loop -> fully resident in one round
  axial_attn_mfma<1><<<dim3(128, 4), dim3(512), 0, stream>>>(Q, K, V, nullptr, flag, 0);
  // pass 2 in two b-halves (xu fits dead xb region); 512 blocks per half
  for (int half = 0; half < 2; half++) {
    axial_attn_mfma<2><<<dim3(128, 2, 2), dim3(512), 0, stream>>>(Q, K, V, xuf, flag, half * 2);
    out_interleave<<<dim3(8, 128, 2), blk, 0, stream>>>(xuf, d_out, flag, half * 2);
  }
}